// Round 1
// baseline (239.442 us; speedup 1.0000x reference)
//
#include <hip/hip_runtime.h>
#include <hip/hip_bf16.h>

// Problem: GPT2 attention. B=2, S=2048, D=1024, H=16, DH=64.
// inputs (f32): x[2,2048,1024], w_attn[1024,3072], b_attn[3072], w_proj[1024,1024], b_proj[1024]
// output (f32): [2,2048,1024]

#define BB 2
#define SS 2048
#define DD 1024
#define HH 16
#define DHH 64
#define MTOK (BB * SS)        // 4096
#define N3D (3 * DD)          // 3072

typedef __attribute__((ext_vector_type(8))) short bf16x8;
typedef __attribute__((ext_vector_type(4))) float f32x4;
typedef __attribute__((ext_vector_type(4))) short short4v;

__device__ __forceinline__ short f2bf(float f) {
  unsigned int x = __float_as_uint(f);
  unsigned int r = (x + 0x7fffu + ((x >> 16) & 1u)) >> 16;
  return (short)r;
}

// ---------------- cast f32 -> bf16 (vectorized x4) ----------------
__global__ void cast_bf16_k(const float* __restrict__ in, short* __restrict__ out, int n4) {
  int i = blockIdx.x * blockDim.x + threadIdx.x;
  if (i < n4) {
    float4 v = reinterpret_cast<const float4*>(in)[i];
    short4v o;
    o[0] = f2bf(v.x); o[1] = f2bf(v.y); o[2] = f2bf(v.z); o[3] = f2bf(v.w);
    reinterpret_cast<short4v*>(out)[i] = o;
  }
}

// ---------------- transpose + cast: W[K][N] f32 -> Wt[N][K] bf16 ----------------
__global__ void transpose_cast_k(const float* __restrict__ W, short* __restrict__ Wt, int K, int N) {
  __shared__ float t[32][33];
  int n0 = blockIdx.x * 32, k0 = blockIdx.y * 32;
  int tx = threadIdx.x, ty = threadIdx.y;
#pragma unroll
  for (int i = 0; i < 4; ++i)
    t[ty + 8 * i][tx] = W[(size_t)(k0 + ty + 8 * i) * N + n0 + tx];
  __syncthreads();
#pragma unroll
  for (int i = 0; i < 4; ++i)
    Wt[(size_t)(n0 + ty + 8 * i) * K + k0 + tx] = f2bf(t[tx][ty + 8 * i]);
}

// ---------------- extract V^T per (b,h): Vt[(b*H+h)*64+d][s] = qkv[b,s, 2048 + h*64 + d] ----------------
__global__ void extract_vt_k(const short* __restrict__ qkv, short* __restrict__ vt) {
  __shared__ short t[32][33];
  int s0 = blockIdx.x * 32, d0 = blockIdx.y * 32;
  int bh = blockIdx.z;
  int b = bh >> 4, h = bh & 15;
  int tx = threadIdx.x, ty = threadIdx.y;
#pragma unroll
  for (int i = 0; i < 4; ++i)
    t[ty + 8 * i][tx] =
        qkv[(size_t)(b * SS + s0 + ty + 8 * i) * N3D + 2 * DD + h * DHH + d0 + tx];
  __syncthreads();
#pragma unroll
  for (int i = 0; i < 4; ++i)
    vt[(size_t)(bh * DHH + d0 + ty + 8 * i) * SS + s0 + tx] = t[tx][ty + 8 * i];
}

// ---------------- GEMM: C[M][N] = A[M][K] * Bt[N][K]^T + bias ----------------
// A, Bt bf16 row-major (K inner). 64x64 tile, 4 waves, 16x16x32 MFMA.
template <int OUTF32>
__global__ __launch_bounds__(256) void gemm_bt_k(const short* __restrict__ A,
                                                 const short* __restrict__ Bt,
                                                 const float* __restrict__ bias,
                                                 void* __restrict__ Cout,
                                                 int M, int N, int K) {
  __shared__ short As[64][72];
  __shared__ short Bs[64][72];
  int tid = threadIdx.x;
  int m0 = blockIdx.y * 64, n0 = blockIdx.x * 64;
  int w = tid >> 6, lane = tid & 63;
  int wr = w >> 1, wc = w & 1;
  int ln16 = lane & 15, l16 = lane >> 4;
  int r0 = tid >> 3, cc0 = (tid & 7) << 3;

  f32x4 acc[2][2] = {};

  for (int k0 = 0; k0 < K; k0 += 64) {
    *reinterpret_cast<uint4*>(&As[r0][cc0]) =
        *reinterpret_cast<const uint4*>(&A[(size_t)(m0 + r0) * K + k0 + cc0]);
    *reinterpret_cast<uint4*>(&As[r0 + 32][cc0]) =
        *reinterpret_cast<const uint4*>(&A[(size_t)(m0 + r0 + 32) * K + k0 + cc0]);
    *reinterpret_cast<uint4*>(&Bs[r0][cc0]) =
        *reinterpret_cast<const uint4*>(&Bt[(size_t)(n0 + r0) * K + k0 + cc0]);
    *reinterpret_cast<uint4*>(&Bs[r0 + 32][cc0]) =
        *reinterpret_cast<const uint4*>(&Bt[(size_t)(n0 + r0 + 32) * K + k0 + cc0]);
    __syncthreads();
#pragma unroll
    for (int kk = 0; kk < 64; kk += 32) {
      bf16x8 a[2], b[2];
      a[0] = *reinterpret_cast<const bf16x8*>(&As[wr * 32 + ln16][kk + l16 * 8]);
      a[1] = *reinterpret_cast<const bf16x8*>(&As[wr * 32 + 16 + ln16][kk + l16 * 8]);
      b[0] = *reinterpret_cast<const bf16x8*>(&Bs[wc * 32 + ln16][kk + l16 * 8]);
      b[1] = *reinterpret_cast<const bf16x8*>(&Bs[wc * 32 + 16 + ln16][kk + l16 * 8]);
#pragma unroll
      for (int mi = 0; mi < 2; ++mi)
#pragma unroll
        for (int ni = 0; ni < 2; ++ni)
          acc[mi][ni] = __builtin_amdgcn_mfma_f32_16x16x32_bf16(a[mi], b[ni], acc[mi][ni], 0, 0, 0);
    }
    __syncthreads();
  }

#pragma unroll
  for (int mi = 0; mi < 2; ++mi)
#pragma unroll
    for (int ni = 0; ni < 2; ++ni)
#pragma unroll
      for (int ri = 0; ri < 4; ++ri) {
        int row = m0 + wr * 32 + mi * 16 + l16 * 4 + ri;
        int col = n0 + wc * 32 + ni * 16 + ln16;
        float v = acc[mi][ni][ri] + bias[col];
        if (OUTF32)
          reinterpret_cast<float*>(Cout)[(size_t)row * N + col] = v;
        else
          reinterpret_cast<short*>(Cout)[(size_t)row * N + col] = f2bf(v);
      }
}

// ---------------- Flash attention ----------------
// grid (S/64, B*H), 256 threads (4 waves). Each block: 64 q-rows of one head.
__global__ __launch_bounds__(256) void flash_attn_k(const short* __restrict__ qkv,
                                                    const short* __restrict__ vt,
                                                    short* __restrict__ ctx) {
  __shared__ short Qs[64][72], Ks[64][72], Vs[64][72], Ps[64][72];
  __shared__ float Ss[64][66];
  __shared__ float pm[64][4], psum[64][4];
  __shared__ float mrow[64], lrow[64], rscale[64];

  int tid = threadIdx.x;
  int qt = blockIdx.x;  // q tile
  int bh = blockIdx.y;
  int b = bh >> 4, h = bh & 15;
  int q0 = qt * 64;
  int w = tid >> 6, lane = tid & 63;
  int wr = w >> 1, wc = w & 1;
  int ln16 = lane & 15, l16 = lane >> 4;
  int r0 = tid >> 3, cc0 = (tid & 7) << 3;

  // stage Q (once)
  *reinterpret_cast<uint4*>(&Qs[r0][cc0]) = *reinterpret_cast<const uint4*>(
      &qkv[(size_t)(b * SS + q0 + r0) * N3D + h * DHH + cc0]);
  *reinterpret_cast<uint4*>(&Qs[r0 + 32][cc0]) = *reinterpret_cast<const uint4*>(
      &qkv[(size_t)(b * SS + q0 + r0 + 32) * N3D + h * DHH + cc0]);
  if (tid < 64) { mrow[tid] = -1e30f; lrow[tid] = 0.f; }

  f32x4 cacc[2][2] = {};

  for (int kt = 0; kt <= qt; ++kt) {
    // stage K tile and V^T tile
    *reinterpret_cast<uint4*>(&Ks[r0][cc0]) = *reinterpret_cast<const uint4*>(
        &qkv[(size_t)(b * SS + kt * 64 + r0) * N3D + DD + h * DHH + cc0]);
    *reinterpret_cast<uint4*>(&Ks[r0 + 32][cc0]) = *reinterpret_cast<const uint4*>(
        &qkv[(size_t)(b * SS + kt * 64 + r0 + 32) * N3D + DD + h * DHH + cc0]);
    *reinterpret_cast<uint4*>(&Vs[r0][cc0]) = *reinterpret_cast<const uint4*>(
        &vt[(size_t)(bh * DHH + r0) * SS + kt * 64 + cc0]);
    *reinterpret_cast<uint4*>(&Vs[r0 + 32][cc0]) = *reinterpret_cast<const uint4*>(
        &vt[(size_t)(bh * DHH + r0 + 32) * SS + kt * 64 + cc0]);
    __syncthreads();

    // S = Q K^T (each wave: 32x32 quadrant)
    f32x4 sacc[2][2] = {};
#pragma unroll
    for (int kk = 0; kk < 64; kk += 32) {
      bf16x8 a[2], bb[2];
      a[0] = *reinterpret_cast<const bf16x8*>(&Qs[wr * 32 + ln16][kk + l16 * 8]);
      a[1] = *reinterpret_cast<const bf16x8*>(&Qs[wr * 32 + 16 + ln16][kk + l16 * 8]);
      bb[0] = *reinterpret_cast<const bf16x8*>(&Ks[wc * 32 + ln16][kk + l16 * 8]);
      bb[1] = *reinterpret_cast<const bf16x8*>(&Ks[wc * 32 + 16 + ln16][kk + l16 * 8]);
#pragma unroll
      for (int mi = 0; mi < 2; ++mi)
#pragma unroll
        for (int ni = 0; ni < 2; ++ni)
          sacc[mi][ni] = __builtin_amdgcn_mfma_f32_16x16x32_bf16(a[mi], bb[ni], sacc[mi][ni], 0, 0, 0);
    }
    // write scores (scaled, causal-masked) to LDS
    bool diag = (kt == qt);
#pragma unroll
    for (int mi = 0; mi < 2; ++mi)
#pragma unroll
      for (int ni = 0; ni < 2; ++ni)
#pragma unroll
        for (int ri = 0; ri < 4; ++ri) {
          int ql = wr * 32 + mi * 16 + l16 * 4 + ri;
          int kl = wc * 32 + ni * 16 + ln16;
          float v = sacc[mi][ni][ri] * 0.125f;  // 1/sqrt(64)
          if (diag && kl > ql) v = -1e30f;
          Ss[ql][kl] = v;
        }
    __syncthreads();

    // online softmax: 4 threads per row, 16 cols each
    {
      int r = tid >> 2, sub = tid & 3;
      int c0 = sub * 16;
      float mx = -1e30f;
#pragma unroll
      for (int c = 0; c < 16; ++c) mx = fmaxf(mx, Ss[r][c0 + c]);
      pm[r][sub] = mx;
      __syncthreads();
      float tm = fmaxf(fmaxf(pm[r][0], pm[r][1]), fmaxf(pm[r][2], pm[r][3]));
      float mold = mrow[r];
      float mnew = fmaxf(mold, tm);
      float scal = __expf(mold - mnew);
      float sum = 0.f;
#pragma unroll
      for (int c = 0; c < 16; ++c) {
        float p = __expf(Ss[r][c0 + c] - mnew);
        Ps[r][c0 + c] = f2bf(p);
        sum += p;
      }
      psum[r][sub] = sum;
      __syncthreads();
      if (sub == 0) {
        lrow[r] = lrow[r] * scal + (psum[r][0] + psum[r][1] + psum[r][2] + psum[r][3]);
        mrow[r] = mnew;
        rscale[r] = scal;
      }
      __syncthreads();
    }

    // rescale ctx accumulator
#pragma unroll
    for (int mi = 0; mi < 2; ++mi)
#pragma unroll
      for (int ni = 0; ni < 2; ++ni)
#pragma unroll
        for (int ri = 0; ri < 4; ++ri) {
          int ql = wr * 32 + mi * 16 + l16 * 4 + ri;
          cacc[mi][ni][ri] *= rscale[ql];
        }

    // ctx += P * V   (B operand from Vt tile: Vs[d][s])
#pragma unroll
    for (int kk = 0; kk < 64; kk += 32) {
      bf16x8 pa[2], vb[2];
      pa[0] = *reinterpret_cast<const bf16x8*>(&Ps[wr * 32 + ln16][kk + l16 * 8]);
      pa[1] = *reinterpret_cast<const bf16x8*>(&Ps[wr * 32 + 16 + ln16][kk + l16 * 8]);
      vb[0] = *reinterpret_cast<const bf16x8*>(&Vs[wc * 32 + ln16][kk + l16 * 8]);
      vb[1] = *reinterpret_cast<const bf16x8*>(&Vs[wc * 32 + 16 + ln16][kk + l16 * 8]);
#pragma unroll
      for (int mi = 0; mi < 2; ++mi)
#pragma unroll
        for (int ni = 0; ni < 2; ++ni)
          cacc[mi][ni] = __builtin_amdgcn_mfma_f32_16x16x32_bf16(pa[mi], vb[ni], cacc[mi][ni], 0, 0, 0);
    }
    __syncthreads();
  }

  // epilogue: ctx = cacc / l
#pragma unroll
  for (int mi = 0; mi < 2; ++mi)
#pragma unroll
    for (int ni = 0; ni < 2; ++ni)
#pragma unroll
      for (int ri = 0; ri < 4; ++ri) {
        int ql = wr * 32 + mi * 16 + l16 * 4 + ri;
        int dl = wc * 32 + ni * 16 + ln16;
        float v = cacc[mi][ni][ri] / lrow[ql];
        ctx[(size_t)(b * SS + q0 + ql) * DD + h * DHH + dl] = f2bf(v);
      }
}

extern "C" void kernel_launch(void* const* d_in, const int* in_sizes, int n_in,
                              void* d_out, int out_size, void* d_ws, size_t ws_size,
                              hipStream_t stream) {
  const float* x      = (const float*)d_in[0];
  const float* w_attn = (const float*)d_in[1];
  const float* b_attn = (const float*)d_in[2];
  const float* w_proj = (const float*)d_in[3];
  const float* b_proj = (const float*)d_in[4];
  float* out = (float*)d_out;

  char* ws = (char*)d_ws;
  // workspace layout (bytes)
  short* xb     = (short*)(ws);                       // 4096*1024*2   = 8388608
  short* wattnT = (short*)(ws + 8388608);             // 3072*1024*2   = 6291456
  short* wprojT = (short*)(ws + 14680064);            // 1024*1024*2   = 2097152
  short* qkv    = (short*)(ws + 16777216);            // 4096*3072*2   = 25165824
  short* vt     = (short*)(ws + 41943040);            // 2*16*64*2048*2= 8388608
  short* ctx    = (short*)(ws + 50331648);            // 4096*1024*2   = 8388608
  // total: 58720256 bytes

  // 1. cast x -> bf16
  {
    int n4 = (MTOK * DD) / 4;
    cast_bf16_k<<<(n4 + 255) / 256, 256, 0, stream>>>(x, xb, n4);
  }
  // 2. transpose-cast weights
  transpose_cast_k<<<dim3(N3D / 32, DD / 32), dim3(32, 8), 0, stream>>>(w_attn, wattnT, DD, N3D);
  transpose_cast_k<<<dim3(DD / 32, DD / 32), dim3(32, 8), 0, stream>>>(w_proj, wprojT, DD, DD);
  // 3. QKV GEMM: qkv[4096][3072] bf16
  gemm_bt_k<0><<<dim3(N3D / 64, MTOK / 64), 256, 0, stream>>>(xb, wattnT, b_attn, qkv, MTOK, N3D, DD);
  // 4. extract V^T
  extract_vt_k<<<dim3(SS / 32, DHH / 32, BB * HH), dim3(32, 8), 0, stream>>>(qkv, vt);
  // 5. flash attention -> ctx bf16 [4096][1024]
  flash_attn_k<<<dim3(SS / 64, BB * HH), 256, 0, stream>>>(qkv, vt, ctx);
  // 6. output projection -> f32 out
  gemm_bt_k<1><<<dim3(DD / 64, MTOK / 64), 256, 0, stream>>>(ctx, wprojT, b_proj, out, MTOK, DD, DD);
}

// Round 2
// 205.324 us; speedup vs baseline: 1.1662x; 1.1662x over previous
//
#include <hip/hip_runtime.h>
#include <hip/hip_bf16.h>

// GPT2 attention. B=2, S=2048, D=1024, H=16, DH=64.
// inputs (f32): x[2,2048,1024], w_attn[1024,3072], b_attn[3072], w_proj[1024,1024], b_proj[1024]
// output (f32): [2,2048,1024]

#define BB 2
#define SS 2048
#define DD 1024
#define HH 16
#define DHH 64
#define MTOK (BB * SS)        // 4096
#define N3D (3 * DD)          // 3072

typedef __attribute__((ext_vector_type(8))) short bf16x8;
typedef __attribute__((ext_vector_type(4))) float f32x4;
typedef __attribute__((ext_vector_type(4))) short short4v;

__device__ __forceinline__ short f2bf(float f) {
  unsigned int x = __float_as_uint(f);
  unsigned int r = (x + 0x7fffu + ((x >> 16) & 1u)) >> 16;
  return (short)r;
}

// ---------------- cast f32 -> bf16 (vectorized x4) ----------------
__global__ void cast_bf16_k(const float* __restrict__ in, short* __restrict__ out, int n4) {
  int i = blockIdx.x * blockDim.x + threadIdx.x;
  if (i < n4) {
    float4 v = reinterpret_cast<const float4*>(in)[i];
    short4v o;
    o[0] = f2bf(v.x); o[1] = f2bf(v.y); o[2] = f2bf(v.z); o[3] = f2bf(v.w);
    reinterpret_cast<short4v*>(out)[i] = o;
  }
}

// ---------------- transpose + cast: W[K][N] f32 -> Wt[N][K] bf16 ----------------
__global__ void transpose_cast_k(const float* __restrict__ W, short* __restrict__ Wt, int K, int N) {
  __shared__ float t[32][33];
  int n0 = blockIdx.x * 32, k0 = blockIdx.y * 32;
  int tx = threadIdx.x, ty = threadIdx.y;
#pragma unroll
  for (int i = 0; i < 4; ++i)
    t[ty + 8 * i][tx] = W[(size_t)(k0 + ty + 8 * i) * N + n0 + tx];
  __syncthreads();
#pragma unroll
  for (int i = 0; i < 4; ++i)
    Wt[(size_t)(n0 + ty + 8 * i) * K + k0 + tx] = f2bf(t[tx][ty + 8 * i]);
}

// ---------------- extract V^T per (b,h): Vt[(b*H+h)*64+d][s] ----------------
__global__ void extract_vt_k(const short* __restrict__ qkv, short* __restrict__ vt) {
  __shared__ short t[32][33];
  int s0 = blockIdx.x * 32, d0 = blockIdx.y * 32;
  int bh = blockIdx.z;
  int b = bh >> 4, h = bh & 15;
  int tx = threadIdx.x, ty = threadIdx.y;
#pragma unroll
  for (int i = 0; i < 4; ++i)
    t[ty + 8 * i][tx] =
        qkv[(size_t)(b * SS + s0 + ty + 8 * i) * N3D + 2 * DD + h * DHH + d0 + tx];
  __syncthreads();
#pragma unroll
  for (int i = 0; i < 4; ++i)
    vt[(size_t)(bh * DHH + d0 + ty + 8 * i) * SS + s0 + tx] = t[tx][ty + 8 * i];
}

// ---------------- GEMM m97-structure: C[M][N] = A[M][K] * Bt[N][K]^T + bias ----------------
// 128x128 tile, BK=64, 4 waves (2x2), global_load_lds w=16, XOR-swizzled LDS.
template <int OUTF32>
__global__ __launch_bounds__(256) void gemm128_k(const short* __restrict__ A,
                                                 const short* __restrict__ Bt,
                                                 const float* __restrict__ bias,
                                                 void* __restrict__ Cout,
                                                 int M, int N, int K) {
  __shared__ short As[128 * 64];
  __shared__ short Bs[128 * 64];
  int tid = threadIdx.x;
  int m0 = blockIdx.y * 128, n0 = blockIdx.x * 128;
  int w = tid >> 6, lane = tid & 63;
  int wr = w >> 1, wc = w & 1;
  int ln16 = lane & 15, l16 = lane >> 4;

  f32x4 acc[4][4] = {};

  // staging: per wave, 4 chunks of 1024B per buffer; lane dest = chunkbase + lane*16
  int lrow0 = w * 32 + (lane >> 3);  // physical row for chunk i=0
  int blk_p = lane & 7;              // physical 16B-block within row

  for (int k0 = 0; k0 < K; k0 += 64) {
#pragma unroll
    for (int i = 0; i < 4; ++i) {
      int row_p = lrow0 + i * 8;
      int colE = ((blk_p ^ (row_p & 7)) << 3);  // swizzled source column (elements)
      __builtin_amdgcn_global_load_lds(
          (const __attribute__((address_space(1))) unsigned int*)&A[(size_t)(m0 + row_p) * K + k0 + colE],
          (__attribute__((address_space(3))) unsigned int*)&As[(w * 4 + i) * 512],
          16, 0, 0);
      __builtin_amdgcn_global_load_lds(
          (const __attribute__((address_space(1))) unsigned int*)&Bt[(size_t)(n0 + row_p) * K + k0 + colE],
          (__attribute__((address_space(3))) unsigned int*)&Bs[(w * 4 + i) * 512],
          16, 0, 0);
    }
    __syncthreads();
#pragma unroll
    for (int kk = 0; kk < 2; ++kk) {
      bf16x8 a[4], bfr[4];
#pragma unroll
      for (int mi = 0; mi < 4; ++mi) {
        int row = wr * 64 + mi * 16 + ln16;
        int blk = (kk * 4 + l16) ^ (row & 7);
        a[mi] = *reinterpret_cast<const bf16x8*>(&As[row * 64 + blk * 8]);
      }
#pragma unroll
      for (int ni = 0; ni < 4; ++ni) {
        int row = wc * 64 + ni * 16 + ln16;
        int blk = (kk * 4 + l16) ^ (row & 7);
        bfr[ni] = *reinterpret_cast<const bf16x8*>(&Bs[row * 64 + blk * 8]);
      }
#pragma unroll
      for (int mi = 0; mi < 4; ++mi)
#pragma unroll
        for (int ni = 0; ni < 4; ++ni)
          acc[mi][ni] = __builtin_amdgcn_mfma_f32_16x16x32_bf16(a[mi], bfr[ni], acc[mi][ni], 0, 0, 0);
    }
    __syncthreads();
  }

#pragma unroll
  for (int mi = 0; mi < 4; ++mi)
#pragma unroll
    for (int ni = 0; ni < 4; ++ni)
#pragma unroll
      for (int ri = 0; ri < 4; ++ri) {
        int row = m0 + wr * 64 + mi * 16 + l16 * 4 + ri;
        int col = n0 + wc * 64 + ni * 16 + ln16;
        float v = acc[mi][ni][ri] + bias[col];
        if (OUTF32)
          reinterpret_cast<float*>(Cout)[(size_t)row * N + col] = v;
        else
          reinterpret_cast<short*>(Cout)[(size_t)row * N + col] = f2bf(v);
      }
}

// ---------------- Flash attention, wave-owns-rows, in-register softmax ----------------
// grid (S/64, B*H), 256 threads (4 waves). Wave w: q-rows [w*16, w*16+16) of the tile.
__global__ __launch_bounds__(256) void flash_attn_k(const short* __restrict__ qkv,
                                                    const short* __restrict__ vt,
                                                    short* __restrict__ ctx) {
  __shared__ short Ks[64][72], Vs[64][72];
  __shared__ short Ps[4][16][72];

  int tid = threadIdx.x;
  int qt = gridDim.x - 1 - blockIdx.x;  // big tiles first (load balance)
  int bh = blockIdx.y;
  int b = bh >> 4, h = bh & 15;
  int q0 = qt * 64;
  int w = tid >> 6, lane = tid & 63;
  int ln16 = lane & 15, l16 = lane >> 4;
  int r0 = tid >> 3, cc0 = (tid & 7) << 3;

  // Q fragments in registers (A-layout: row=ln16, k=kk*32+l16*8..)
  bf16x8 qf[2];
  {
    const short* qrow = &qkv[(size_t)(b * SS + q0 + w * 16 + ln16) * N3D + h * DHH];
    qf[0] = *reinterpret_cast<const bf16x8*>(qrow + l16 * 8);
    qf[1] = *reinterpret_cast<const bf16x8*>(qrow + 32 + l16 * 8);
  }
  float m_[4] = {-1e30f, -1e30f, -1e30f, -1e30f};
  float l_[4] = {0.f, 0.f, 0.f, 0.f};
  f32x4 cacc[4] = {};

  for (int kt = 0; kt <= qt; ++kt) {
    // stage K tile (row=s, col=d) and V^T tile (row=d, col=s)
    *reinterpret_cast<uint4*>(&Ks[r0][cc0]) = *reinterpret_cast<const uint4*>(
        &qkv[(size_t)(b * SS + kt * 64 + r0) * N3D + DD + h * DHH + cc0]);
    *reinterpret_cast<uint4*>(&Ks[r0 + 32][cc0]) = *reinterpret_cast<const uint4*>(
        &qkv[(size_t)(b * SS + kt * 64 + r0 + 32) * N3D + DD + h * DHH + cc0]);
    *reinterpret_cast<uint4*>(&Vs[r0][cc0]) = *reinterpret_cast<const uint4*>(
        &vt[(size_t)(bh * DHH + r0) * SS + kt * 64 + cc0]);
    *reinterpret_cast<uint4*>(&Vs[r0 + 32][cc0]) = *reinterpret_cast<const uint4*>(
        &vt[(size_t)(bh * DHH + r0 + 32) * SS + kt * 64 + cc0]);
    __syncthreads();

    // S_w = Q_w (16x64) @ K^T : sacc[ni], C-layout row=l16*4+ri, col=ni*16+ln16
    f32x4 sacc[4] = {};
#pragma unroll
    for (int kk = 0; kk < 2; ++kk)
#pragma unroll
      for (int ni = 0; ni < 4; ++ni) {
        bf16x8 bfr = *reinterpret_cast<const bf16x8*>(&Ks[ni * 16 + ln16][kk * 32 + l16 * 8]);
        sacc[ni] = __builtin_amdgcn_mfma_f32_16x16x32_bf16(qf[kk], bfr, sacc[ni], 0, 0, 0);
      }

    bool diag = (kt == qt);
    float p[4][4];  // [ni][ri]
#pragma unroll
    for (int ri = 0; ri < 4; ++ri) {
      int ql = w * 16 + l16 * 4 + ri;  // q-row within 64-tile
      float mx = -1e30f;
#pragma unroll
      for (int ni = 0; ni < 4; ++ni) {
        float v = sacc[ni][ri] * 0.125f;  // 1/sqrt(64)
        if (diag && (ni * 16 + ln16) > ql) v = -1e30f;
        p[ni][ri] = v;
        mx = fmaxf(mx, v);
      }
#pragma unroll
      for (int off = 1; off < 16; off <<= 1) mx = fmaxf(mx, __shfl_xor(mx, off));
      float mo = m_[ri], mn = fmaxf(mo, mx);
      float sc = __expf(mo - mn);
      float sum = 0.f;
#pragma unroll
      for (int ni = 0; ni < 4; ++ni) {
        float e = __expf(p[ni][ri] - mn);
        p[ni][ri] = e;
        sum += e;
      }
#pragma unroll
      for (int off = 1; off < 16; off <<= 1) sum += __shfl_xor(sum, off);
      m_[ri] = mn;
      l_[ri] = l_[ri] * sc + sum;
#pragma unroll
      for (int di = 0; di < 4; ++di) cacc[di][ri] *= sc;
#pragma unroll
      for (int ni = 0; ni < 4; ++ni)
        Ps[w][l16 * 4 + ri][ni * 16 + ln16] = f2bf(p[ni][ri]);
    }
    // Ps write -> read is same-wave; DS ops complete in order, just drain lgkm.
    asm volatile("s_waitcnt lgkmcnt(0)" ::: "memory");

    // ctx_w (16x64) += P_w (16x64) @ V (64x64)
#pragma unroll
    for (int kk = 0; kk < 2; ++kk) {
      bf16x8 pa = *reinterpret_cast<const bf16x8*>(&Ps[w][ln16][kk * 32 + l16 * 8]);
#pragma unroll
      for (int di = 0; di < 4; ++di) {
        bf16x8 vb = *reinterpret_cast<const bf16x8*>(&Vs[di * 16 + ln16][kk * 32 + l16 * 8]);
        cacc[di] = __builtin_amdgcn_mfma_f32_16x16x32_bf16(pa, vb, cacc[di], 0, 0, 0);
      }
    }
    __syncthreads();
  }

  // epilogue
#pragma unroll
  for (int di = 0; di < 4; ++di)
#pragma unroll
    for (int ri = 0; ri < 4; ++ri) {
      int row = q0 + w * 16 + l16 * 4 + ri;
      int col = h * DHH + di * 16 + ln16;
      ctx[(size_t)(b * SS + row) * DD + col] = f2bf(cacc[di][ri] / l_[ri]);
    }
}

extern "C" void kernel_launch(void* const* d_in, const int* in_sizes, int n_in,
                              void* d_out, int out_size, void* d_ws, size_t ws_size,
                              hipStream_t stream) {
  const float* x      = (const float*)d_in[0];
  const float* w_attn = (const float*)d_in[1];
  const float* b_attn = (const float*)d_in[2];
  const float* w_proj = (const float*)d_in[3];
  const float* b_proj = (const float*)d_in[4];
  float* out = (float*)d_out;

  char* ws = (char*)d_ws;
  short* xb     = (short*)(ws);                       // 8388608 B
  short* wattnT = (short*)(ws + 8388608);             // 6291456 B
  short* wprojT = (short*)(ws + 14680064);            // 2097152 B
  short* qkv    = (short*)(ws + 16777216);            // 25165824 B
  short* vt     = (short*)(ws + 41943040);            // 8388608 B
  short* ctx    = (short*)(ws + 50331648);            // 8388608 B

  {
    int n4 = (MTOK * DD) / 4;
    cast_bf16_k<<<(n4 + 255) / 256, 256, 0, stream>>>(x, xb, n4);
  }
  transpose_cast_k<<<dim3(N3D / 32, DD / 32), dim3(32, 8), 0, stream>>>(w_attn, wattnT, DD, N3D);
  transpose_cast_k<<<dim3(DD / 32, DD / 32), dim3(32, 8), 0, stream>>>(w_proj, wprojT, DD, DD);
  gemm128_k<0><<<dim3(N3D / 128, MTOK / 128), 256, 0, stream>>>(xb, wattnT, b_attn, qkv, MTOK, N3D, DD);
  extract_vt_k<<<dim3(SS / 32, DHH / 32, BB * HH), dim3(32, 8), 0, stream>>>(qkv, vt);
  flash_attn_k<<<dim3(SS / 64, BB * HH), 256, 0, stream>>>(qkv, vt, ctx);
  gemm128_k<1><<<dim3(DD / 128, MTOK / 128), 256, 0, stream>>>(ctx, wprojT, b_proj, out, MTOK, DD, DD);
}

// Round 3
// 130.231 us; speedup vs baseline: 1.8386x; 1.5766x over previous
//
#include <hip/hip_runtime.h>
#include <hip/hip_bf16.h>

// GPT2 attention. B=2, S=2048, D=1024, H=16, DH=64.
// inputs (f32): x[2,2048,1024], w_attn[1024,3072], b_attn[3072], w_proj[1024,1024], b_proj[1024]
// output (f32): [2,2048,1024]

#define BB 2
#define SS 2048
#define DD 1024
#define HH 16
#define DHH 64
#define MTOK (BB * SS)        // 4096
#define N3D (3 * DD)          // 3072

typedef __attribute__((ext_vector_type(8))) short bf16x8;
typedef __attribute__((ext_vector_type(4))) float f32x4;
typedef __attribute__((ext_vector_type(4))) short short4v;

__device__ __forceinline__ short f2bf(float f) {
  unsigned int x = __float_as_uint(f);
  unsigned int r = (x + 0x7fffu + ((x >> 16) & 1u)) >> 16;
  return (short)r;
}

__device__ __forceinline__ unsigned int cvtpk_bf16(float lo, float hi) {
  unsigned int r;
  asm("v_cvt_pk_bf16_f32 %0, %1, %2" : "=v"(r) : "v"(lo), "v"(hi));
  return r;
}

// ---------------- cast f32 -> bf16 (vectorized x4) ----------------
__global__ void cast_bf16_k(const float* __restrict__ in, short* __restrict__ out, int n4) {
  int i = blockIdx.x * blockDim.x + threadIdx.x;
  if (i < n4) {
    float4 v = reinterpret_cast<const float4*>(in)[i];
    short4v o;
    o[0] = f2bf(v.x); o[1] = f2bf(v.y); o[2] = f2bf(v.z); o[3] = f2bf(v.w);
    reinterpret_cast<short4v*>(out)[i] = o;
  }
}

// ---------------- transpose + cast: W[K][N] f32 -> Wt[N][K] bf16 ----------------
__global__ void transpose_cast_k(const float* __restrict__ W, short* __restrict__ Wt, int K, int N) {
  __shared__ float t[32][33];
  int n0 = blockIdx.x * 32, k0 = blockIdx.y * 32;
  int tx = threadIdx.x, ty = threadIdx.y;
#pragma unroll
  for (int i = 0; i < 4; ++i)
    t[ty + 8 * i][tx] = W[(size_t)(k0 + ty + 8 * i) * N + n0 + tx];
  __syncthreads();
#pragma unroll
  for (int i = 0; i < 4; ++i)
    Wt[(size_t)(n0 + ty + 8 * i) * K + k0 + tx] = f2bf(t[tx][ty + 8 * i]);
}

// ---------------- extract V^T per (b,h): Vt[(b*H+h)*64+d][s] ----------------
__global__ void extract_vt_k(const short* __restrict__ qkv, short* __restrict__ vt) {
  __shared__ short t[32][33];
  int s0 = blockIdx.x * 32, d0 = blockIdx.y * 32;
  int bh = blockIdx.z;
  int b = bh >> 4, h = bh & 15;
  int tx = threadIdx.x, ty = threadIdx.y;
#pragma unroll
  for (int i = 0; i < 4; ++i)
    t[ty + 8 * i][tx] =
        qkv[(size_t)(b * SS + s0 + ty + 8 * i) * N3D + 2 * DD + h * DHH + d0 + tx];
  __syncthreads();
#pragma unroll
  for (int i = 0; i < 4; ++i)
    vt[(size_t)(bh * DHH + d0 + ty + 8 * i) * SS + s0 + tx] = t[tx][ty + 8 * i];
}

// ---------------- GEMM m97-structure: C[M][N] = A[M][K] * Bt[N][K]^T + bias ----------------
template <int OUTF32>
__global__ __launch_bounds__(256) void gemm128_k(const short* __restrict__ A,
                                                 const short* __restrict__ Bt,
                                                 const float* __restrict__ bias,
                                                 void* __restrict__ Cout,
                                                 int M, int N, int K) {
  __shared__ short As[128 * 64];
  __shared__ short Bs[128 * 64];
  int tid = threadIdx.x;
  int m0 = blockIdx.y * 128, n0 = blockIdx.x * 128;
  int w = tid >> 6, lane = tid & 63;
  int wr = w >> 1, wc = w & 1;
  int ln16 = lane & 15, l16 = lane >> 4;

  f32x4 acc[4][4] = {};

  int lrow0 = w * 32 + (lane >> 3);
  int blk_p = lane & 7;

  for (int k0 = 0; k0 < K; k0 += 64) {
#pragma unroll
    for (int i = 0; i < 4; ++i) {
      int row_p = lrow0 + i * 8;
      int colE = ((blk_p ^ (row_p & 7)) << 3);
      __builtin_amdgcn_global_load_lds(
          (const __attribute__((address_space(1))) unsigned int*)&A[(size_t)(m0 + row_p) * K + k0 + colE],
          (__attribute__((address_space(3))) unsigned int*)&As[(w * 4 + i) * 512],
          16, 0, 0);
      __builtin_amdgcn_global_load_lds(
          (const __attribute__((address_space(1))) unsigned int*)&Bt[(size_t)(n0 + row_p) * K + k0 + colE],
          (__attribute__((address_space(3))) unsigned int*)&Bs[(w * 4 + i) * 512],
          16, 0, 0);
    }
    __syncthreads();
#pragma unroll
    for (int kk = 0; kk < 2; ++kk) {
      bf16x8 a[4], bfr[4];
#pragma unroll
      for (int mi = 0; mi < 4; ++mi) {
        int row = wr * 64 + mi * 16 + ln16;
        int blk = (kk * 4 + l16) ^ (row & 7);
        a[mi] = *reinterpret_cast<const bf16x8*>(&As[row * 64 + blk * 8]);
      }
#pragma unroll
      for (int ni = 0; ni < 4; ++ni) {
        int row = wc * 64 + ni * 16 + ln16;
        int blk = (kk * 4 + l16) ^ (row & 7);
        bfr[ni] = *reinterpret_cast<const bf16x8*>(&Bs[row * 64 + blk * 8]);
      }
#pragma unroll
      for (int mi = 0; mi < 4; ++mi)
#pragma unroll
        for (int ni = 0; ni < 4; ++ni)
          acc[mi][ni] = __builtin_amdgcn_mfma_f32_16x16x32_bf16(a[mi], bfr[ni], acc[mi][ni], 0, 0, 0);
    }
    __syncthreads();
  }

#pragma unroll
  for (int mi = 0; mi < 4; ++mi)
#pragma unroll
    for (int ni = 0; ni < 4; ++ni)
#pragma unroll
      for (int ri = 0; ri < 4; ++ri) {
        int row = m0 + wr * 64 + mi * 16 + l16 * 4 + ri;
        int col = n0 + wc * 64 + ni * 16 + ln16;
        float v = acc[mi][ni][ri] + bias[col];
        if (OUTF32)
          reinterpret_cast<float*>(Cout)[(size_t)row * N + col] = v;
        else
          reinterpret_cast<short*>(Cout)[(size_t)row * N + col] = f2bf(v);
      }
}

// ---------------- Flash attention: 8 waves, even/odd KV split, paired q-tiles ----------------
// grid (16, B*H), 512 threads. Waves 0-3 (g=0): even kt; waves 4-7 (g=1): odd kt.
// Wave w (=wg&3) owns q-rows [w*16, w*16+16). Block processes q-tiles 31-pj then pj.
__global__ __launch_bounds__(512) void flash_attn_k(const short* __restrict__ qkv,
                                                    const short* __restrict__ vt,
                                                    short* __restrict__ ctx) {
  __shared__ short Ks[2][64][72], Vs[2][64][72];
  __shared__ short Ps[8][16][72];   // also reused as f32 dump region in combine
  __shared__ float m1s[4][16], l1s[4][16];

  int tid = threadIdx.x;
  int pj = blockIdx.x;   // 0..15
  int bh = blockIdx.y;
  int b = bh >> 4, h = bh & 15;
  int wg = tid >> 6, lane = tid & 63;
  int g = wg >> 2, w = wg & 3;
  int ln16 = lane & 15, l16 = lane >> 4;
  int t8 = tid & 255;
  int tb = tid >> 8;                 // staging buffer (tile parity) this thread fills
  int r0 = t8 >> 3, cc0 = (t8 & 7) << 3;

  const short* kbase = qkv + (size_t)(b * SS) * N3D + DD + h * DHH;  // + s*N3D + d
  const short* vbase = vt + (size_t)(bh * DHH) * SS;                 // + d*SS + s

#pragma unroll 1
  for (int ti = 0; ti < 2; ++ti) {
    int qt = ti ? pj : 31 - pj;
    int q0 = qt * 64;

    bf16x8 qf[2];
    {
      const short* qrow = qkv + (size_t)(b * SS + q0 + w * 16 + ln16) * N3D + h * DHH;
      qf[0] = *reinterpret_cast<const bf16x8*>(qrow + l16 * 8);
      qf[1] = *reinterpret_cast<const bf16x8*>(qrow + 32 + l16 * 8);
    }
    float m_ = -1e30f, l_ = 0.f;
    f32x4 cacc[4] = {};

    int ns = (qt + 2) >> 1;
    uint4 kr0, kr1, vr0, vr1;
    {
      int kt_s = tb <= qt ? tb : qt;
      kr0 = *reinterpret_cast<const uint4*>(kbase + (size_t)(kt_s * 64 + r0) * N3D + cc0);
      kr1 = *reinterpret_cast<const uint4*>(kbase + (size_t)(kt_s * 64 + r0 + 32) * N3D + cc0);
      vr0 = *reinterpret_cast<const uint4*>(vbase + (size_t)r0 * SS + kt_s * 64 + cc0);
      vr1 = *reinterpret_cast<const uint4*>(vbase + (size_t)(r0 + 32) * SS + kt_s * 64 + cc0);
    }

#pragma unroll 1
    for (int s = 0; s < ns; ++s) {
      // write staged regs -> LDS (compiler inserts vmcnt wait)
      *reinterpret_cast<uint4*>(&Ks[tb][r0][cc0]) = kr0;
      *reinterpret_cast<uint4*>(&Ks[tb][r0 + 32][cc0]) = kr1;
      *reinterpret_cast<uint4*>(&Vs[tb][r0][cc0]) = vr0;
      *reinterpret_cast<uint4*>(&Vs[tb][r0 + 32][cc0]) = vr1;
      __syncthreads();

      // prefetch next super-iter (clamped; latency hides under softmax+PV)
      {
        int kt_n = 2 * (s + 1) + tb;
        if (kt_n > qt) kt_n = qt;
        kr0 = *reinterpret_cast<const uint4*>(kbase + (size_t)(kt_n * 64 + r0) * N3D + cc0);
        kr1 = *reinterpret_cast<const uint4*>(kbase + (size_t)(kt_n * 64 + r0 + 32) * N3D + cc0);
        vr0 = *reinterpret_cast<const uint4*>(vbase + (size_t)r0 * SS + kt_n * 64 + cc0);
        vr1 = *reinterpret_cast<const uint4*>(vbase + (size_t)(r0 + 32) * SS + kt_n * 64 + cc0);
      }

      int kt_c = 2 * s + g;
      if (kt_c <= qt) {
        // QK^T swapped: sacc[ni][ri] = S^T[k = ni*16+l16*4+ri][q = ln16]
        f32x4 sacc[4] = {};
#pragma unroll
        for (int kk = 0; kk < 2; ++kk)
#pragma unroll
          for (int ni = 0; ni < 4; ++ni) {
            bf16x8 kf = *reinterpret_cast<const bf16x8*>(&Ks[g][ni * 16 + ln16][kk * 32 + l16 * 8]);
            sacc[ni] = __builtin_amdgcn_mfma_f32_16x16x32_bf16(kf, qf[kk], sacc[ni], 0, 0, 0);
          }

        float p[4][4];
        float mx = -1e30f;
        if (kt_c == qt) {
          int qg = q0 + w * 16 + ln16;
#pragma unroll
          for (int ni = 0; ni < 4; ++ni)
#pragma unroll
            for (int ri = 0; ri < 4; ++ri) {
              int kg = kt_c * 64 + ni * 16 + l16 * 4 + ri;
              float v = sacc[ni][ri] * 0.125f;
              if (kg > qg) v = -1e30f;
              p[ni][ri] = v;
              mx = fmaxf(mx, v);
            }
        } else {
#pragma unroll
          for (int ni = 0; ni < 4; ++ni)
#pragma unroll
            for (int ri = 0; ri < 4; ++ri) {
              float v = sacc[ni][ri] * 0.125f;
              p[ni][ri] = v;
              mx = fmaxf(mx, v);
            }
        }
        mx = fmaxf(mx, __shfl_xor(mx, 16));
        mx = fmaxf(mx, __shfl_xor(mx, 32));
        float mn = fmaxf(m_, mx);
        float sc = __expf(m_ - mn);
        float sum = 0.f;
#pragma unroll
        for (int ni = 0; ni < 4; ++ni)
#pragma unroll
          for (int ri = 0; ri < 4; ++ri) {
            float e = __expf(p[ni][ri] - mn);
            p[ni][ri] = e;
            sum += e;
          }
        sum += __shfl_xor(sum, 16);
        sum += __shfl_xor(sum, 32);
        m_ = mn;
        l_ = l_ * sc + sum;

        // pack P -> Ps[wg][q=ln16][k] via cvt_pk, 4x ds_write_b64
#pragma unroll
        for (int ni = 0; ni < 4; ++ni) {
          uint2 u;
          u.x = cvtpk_bf16(p[ni][0], p[ni][1]);
          u.y = cvtpk_bf16(p[ni][2], p[ni][3]);
          *reinterpret_cast<uint2*>(&Ps[wg][ln16][ni * 16 + l16 * 4]) = u;
        }
        // rescale cacc (rows q = l16*4+ri): fetch sc from lane owning that row
        float scr[4];
#pragma unroll
        for (int ri = 0; ri < 4; ++ri) scr[ri] = __shfl(sc, l16 * 4 + ri);
#pragma unroll
        for (int di = 0; di < 4; ++di)
#pragma unroll
          for (int ri = 0; ri < 4; ++ri) cacc[di][ri] *= scr[ri];

        asm volatile("s_waitcnt lgkmcnt(0)" ::: "memory");

        // ctx += P @ V
#pragma unroll
        for (int kk = 0; kk < 2; ++kk) {
          bf16x8 pa = *reinterpret_cast<const bf16x8*>(&Ps[wg][ln16][kk * 32 + l16 * 8]);
#pragma unroll
          for (int di = 0; di < 4; ++di) {
            bf16x8 vb = *reinterpret_cast<const bf16x8*>(&Vs[g][di * 16 + ln16][kk * 32 + l16 * 8]);
            cacc[di] = __builtin_amdgcn_mfma_f32_16x16x32_bf16(pa, vb, cacc[di], 0, 0, 0);
          }
        }
      }
      __syncthreads();
    }

    // ---- combine even/odd partials (in-block) ----
    float* dump = reinterpret_cast<float*>(&Ps[0][0][0]);  // 16KB < 18.4KB
    if (g == 1) {
#pragma unroll
      for (int di = 0; di < 4; ++di)
#pragma unroll
        for (int ri = 0; ri < 4; ++ri)
          dump[w * 1024 + (l16 * 4 + ri) * 64 + di * 16 + ln16] = cacc[di][ri];
      if (l16 == 0) { m1s[w][ln16] = m_; l1s[w][ln16] = l_; }
    }
    __syncthreads();
    if (g == 0) {
      float m1 = m1s[w][ln16], l1 = l1s[w][ln16];
      float mM = fmaxf(m_, m1);
      float e0 = __expf(m_ - mM), e1 = __expf(m1 - mM);
      float inv = 1.f / (l_ * e0 + l1 * e1);
      float e0r[4], e1r[4], ivr[4];
#pragma unroll
      for (int ri = 0; ri < 4; ++ri) {
        int src = l16 * 4 + ri;
        e0r[ri] = __shfl(e0, src);
        e1r[ri] = __shfl(e1, src);
        ivr[ri] = __shfl(inv, src);
      }
#pragma unroll
      for (int di = 0; di < 4; ++di)
#pragma unroll
        for (int ri = 0; ri < 4; ++ri) {
          float a1 = dump[w * 1024 + (l16 * 4 + ri) * 64 + di * 16 + ln16];
          float o = (cacc[di][ri] * e0r[ri] + a1 * e1r[ri]) * ivr[ri];
          int row = q0 + w * 16 + l16 * 4 + ri;
          int col = h * DHH + di * 16 + ln16;
          ctx[(size_t)(b * SS + row) * DD + col] = f2bf(o);
        }
    }
    __syncthreads();
  }
}

extern "C" void kernel_launch(void* const* d_in, const int* in_sizes, int n_in,
                              void* d_out, int out_size, void* d_ws, size_t ws_size,
                              hipStream_t stream) {
  const float* x      = (const float*)d_in[0];
  const float* w_attn = (const float*)d_in[1];
  const float* b_attn = (const float*)d_in[2];
  const float* w_proj = (const float*)d_in[3];
  const float* b_proj = (const float*)d_in[4];
  float* out = (float*)d_out;

  char* ws = (char*)d_ws;
  short* xb     = (short*)(ws);                       // 8388608 B
  short* wattnT = (short*)(ws + 8388608);             // 6291456 B
  short* wprojT = (short*)(ws + 14680064);            // 2097152 B
  short* qkv    = (short*)(ws + 16777216);            // 25165824 B
  short* vt     = (short*)(ws + 41943040);            // 8388608 B
  short* ctx    = (short*)(ws + 50331648);            // 8388608 B

  {
    int n4 = (MTOK * DD) / 4;
    cast_bf16_k<<<(n4 + 255) / 256, 256, 0, stream>>>(x, xb, n4);
  }
  transpose_cast_k<<<dim3(N3D / 32, DD / 32), dim3(32, 8), 0, stream>>>(w_attn, wattnT, DD, N3D);
  transpose_cast_k<<<dim3(DD / 32, DD / 32), dim3(32, 8), 0, stream>>>(w_proj, wprojT, DD, DD);
  gemm128_k<0><<<dim3(N3D / 128, MTOK / 128), 256, 0, stream>>>(xb, wattnT, b_attn, qkv, MTOK, N3D, DD);
  extract_vt_k<<<dim3(SS / 32, DHH / 32, BB * HH), dim3(32, 8), 0, stream>>>(qkv, vt);
  flash_attn_k<<<dim3(16, BB * HH), 512, 0, stream>>>(qkv, vt, ctx);
  gemm128_k<1><<<dim3(DD / 128, MTOK / 128), 256, 0, stream>>>(ctx, wprojT, b_proj, out, MTOK, DD, DD);
}